// Round 6
// baseline (97.041 us; speedup 1.0000x reference)
//
#include <hip/hip_runtime.h>
#include <math.h>

#define BINS 30
#define QDIM 32
#define DDIM 8192
#define NCOPY 8                  // histogram copies (collision dilution)
#define NREP 4                   // diagnostic: repeat each row's pass 4x (idempotent)

// DIAGNOSTIC ROUND. One block per (b,q) row; the full per-row pass (clear,
// histogram, log-write) is repeated NREP times producing identical output
// each time. An opaque zero offset defeats cross-rep CSE so loads/VALU/DS
// all truly execute NREP times, while HBM traffic stays ~1x (row is
// cache-hot on repeats). Purpose: scale compute/DS/L1-L2 work 4x vs HBM 1x
// and push dur_us above the harness fills so rocprof shows our counters.
__global__ __launch_bounds__(256, 8) void drmm_hist_kernel(
    const float* __restrict__ simmat,
    const int*   __restrict__ dtoks,
    const int*   __restrict__ qtoks,
    float*       __restrict__ out)
{
    const int bq = blockIdx.x;                     // row index in [0, B*Q)
    const int b  = bq >> 5;                        // Q == 32
    const int t  = threadIdx.x;
    const int c  = t & (NCOPY - 1);                // this lane's histogram copy

    __shared__ int hist[(BINS + 1) * NCOPY];       // 31 bins x 8 copies

    const bool qvalid = (qtoks[bq] != 0);
    const float4* __restrict__ srow =
        reinterpret_cast<const float4*>(simmat + (size_t)bq * DDIM);
    const int4* __restrict__ drow =
        reinterpret_cast<const int4*>(dtoks + (size_t)b * DDIM);

#pragma unroll 1
    for (int rep = 0; rep < NREP; ++rep) {
        // opaque zero: compiler can't prove addresses match previous rep,
        // so loads are re-issued every rep (defeats CSE; rule #17 idiom)
        int off = 0;
        asm volatile("" : "+v"(off));

        if (t < (BINS + 1) * NCOPY) hist[t] = 0;
        __syncthreads();

#pragma unroll
        for (int it = 0; it < 8; ++it) {
            const int v = it * 256 + t + off;      // float4 index within row
            const float4 s  = srow[v];
            const int4   dt = drow[v];

            // bin = trunc(((s + 1.000001f) / 2.0f) * 29.0f) -- XLA f32 op order
            int bin0 = (int)(((s.x + 1.000001f) / 2.0f) * 29.0f);
            int bin1 = (int)(((s.y + 1.000001f) / 2.0f) * 29.0f);
            int bin2 = (int)(((s.z + 1.000001f) / 2.0f) * 29.0f);
            int bin3 = (int)(((s.w + 1.000001f) / 2.0f) * 29.0f);
            bin0 = min(max(bin0, 0), BINS - 1);
            bin1 = min(max(bin1, 0), BINS - 1);
            bin2 = min(max(bin2, 0), BINS - 1);
            bin3 = min(max(bin3, 0), BINS - 1);
            bin0 = (qvalid && dt.x != 0) ? bin0 : BINS;   // invalid -> trash bin
            bin1 = (qvalid && dt.y != 0) ? bin1 : BINS;
            bin2 = (qvalid && dt.z != 0) ? bin2 : BINS;
            bin3 = (qvalid && dt.w != 0) ? bin3 : BINS;

            atomicAdd(&hist[bin0 * NCOPY + c], 1);
            atomicAdd(&hist[bin1 * NCOPY + c], 1);
            atomicAdd(&hist[bin2 * NCOPY + c], 1);
            atomicAdd(&hist[bin3 * NCOPY + c], 1);
        }
        __syncthreads();

        if (t < BINS) {
            const int* h = &hist[t * NCOPY];
            const int cnt = h[0] + h[1] + h[2] + h[3] + h[4] + h[5] + h[6] + h[7];
            out[(size_t)bq * BINS + t] = logf((float)cnt + 1e-5f);
        }
        __syncthreads();   // reads done before next rep's clear
    }
}

extern "C" void kernel_launch(void* const* d_in, const int* in_sizes, int n_in,
                              void* d_out, int out_size, void* d_ws, size_t ws_size,
                              hipStream_t stream) {
    const float* simmat = (const float*)d_in[0];  // [B,Q,D] f32
    const int*   dtoks  = (const int*)d_in[1];    // [B,D]
    const int*   qtoks  = (const int*)d_in[2];    // [B,Q]
    float*       out    = (float*)d_out;          // [B,Q,BINS]

    const int BQ = in_sizes[2];                   // B*Q = 4096
    drmm_hist_kernel<<<BQ, 256, 0, stream>>>(simmat, dtoks, qtoks, out);
}

// Round 7
// 31.053 us; speedup vs baseline: 3.1250x; 3.1250x over previous
//
#include <hip/hip_runtime.h>
#include <math.h>

#define BINS 30
#define QDIM 32
#define DDIM 8192
#define NCOPY 32                 // one histogram copy per lane-of-half-wave: bank = lane&31

// ---------- kernel 1: pre-packed per-thread validity nibbles ----------
// pmask[b*256 + t] bit (4*it + j) = (dtoks[b][it*1024 + 4*t + j] != 0)
// i.e. exactly the 32 elements that hist-kernel thread t of row-block (b,*)
// processes, in the order it processes them.
__global__ __launch_bounds__(256) void build_mask_kernel(
    const int* __restrict__ dtoks,
    unsigned int* __restrict__ pmask)
{
    const int b = blockIdx.x;
    const int t = threadIdx.x;
    const int4* __restrict__ drow = reinterpret_cast<const int4*>(dtoks + (size_t)b * DDIM);
    unsigned int bits = 0u;
#pragma unroll
    for (int it = 0; it < 8; ++it) {
        const int4 dt = drow[it * 256 + t];
        bits |= (dt.x != 0 ? 1u : 0u) << (4 * it + 0);
        bits |= (dt.y != 0 ? 1u : 0u) << (4 * it + 1);
        bits |= (dt.z != 0 ? 1u : 0u) << (4 * it + 2);
        bits |= (dt.w != 0 ? 1u : 0u) << (4 * it + 3);
    }
    pmask[b * 256 + t] = bits;
}

// ---------- kernel 2: weighted histogram + log ----------
// One block per (b,q) row, 256 threads. Hot loop per float4:
//   5 VALU + 1 ds_add per element, conflict-free banks (addr = bin*32 + lane&31).
// Weights enter as the atomic's VALUE (0 or 1) -- no branches, no trash bin.
__global__ __launch_bounds__(256, 8) void drmm_hist_kernel(
    const float* __restrict__ simmat,
    const unsigned int* __restrict__ pmask,
    const int*   __restrict__ qtoks,
    float*       __restrict__ out)
{
    const int bq = blockIdx.x;        // row index in [0, B*Q)
    const int b  = bq >> 5;           // Q == 32
    const int t  = threadIdx.x;
    const int c  = t & (NCOPY - 1);

    __shared__ int hist[32 * NCOPY];  // 4 KB; bins 0..29 used, padded to 32

    // clear: 16 B per thread
    reinterpret_cast<int4*>(hist)[t] = int4{0, 0, 0, 0};

    // block-uniform early-out for padded query tokens
    if (qtoks[bq] == 0) {
        if (t < BINS) out[(size_t)bq * BINS + t] = logf(1e-5f);
        return;
    }

    const unsigned int nib = pmask[b * 256 + t];   // this thread's 32 weight bits
    const float4* __restrict__ srow =
        reinterpret_cast<const float4*>(simmat + (size_t)bq * DDIM);

    __syncthreads();

    // 8192 elements / (256 threads * 4) = 8 iterations
#pragma unroll
    for (int it = 0; it < 8; ++it) {
        const float4 s = srow[it * 256 + t];
        // bin = trunc((s + 1.000001f) * 14.5f)  == trunc(((s+1.000001f)/2)*29)
        // (/2 is exact; both forms are round(t*14.5) -> bit-identical to XLA)
        const int bin0 = (int)((s.x + 1.000001f) * 14.5f);
        const int bin1 = (int)((s.y + 1.000001f) * 14.5f);
        const int bin2 = (int)((s.z + 1.000001f) * 14.5f);
        const int bin3 = (int)((s.w + 1.000001f) * 14.5f);

        atomicAdd(&hist[bin0 * NCOPY + c], (int)((nib >> (4 * it + 0)) & 1u));
        atomicAdd(&hist[bin1 * NCOPY + c], (int)((nib >> (4 * it + 1)) & 1u));
        atomicAdd(&hist[bin2 * NCOPY + c], (int)((nib >> (4 * it + 2)) & 1u));
        atomicAdd(&hist[bin3 * NCOPY + c], (int)((nib >> (4 * it + 3)) & 1u));
    }
    __syncthreads();

    // reduce 32 copies per bin: 240 threads -> (bin, j), 4 LDS reads each,
    // then 3-step shuffle across the 8-lane j-group.
    if (t < BINS * 8) {
        const int bin = t >> 3;
        const int j   = t & 7;
        int p = hist[bin * NCOPY + j]      + hist[bin * NCOPY + j + 8]
              + hist[bin * NCOPY + j + 16] + hist[bin * NCOPY + j + 24];
        p += __shfl_xor(p, 1);
        p += __shfl_xor(p, 2);
        p += __shfl_xor(p, 4);
        if (j == 0) out[(size_t)bq * BINS + bin] = logf((float)p + 1e-5f);
    }
}

extern "C" void kernel_launch(void* const* d_in, const int* in_sizes, int n_in,
                              void* d_out, int out_size, void* d_ws, size_t ws_size,
                              hipStream_t stream) {
    const float* simmat = (const float*)d_in[0];  // [B,Q,D] f32
    const int*   dtoks  = (const int*)d_in[1];    // [B,D]
    const int*   qtoks  = (const int*)d_in[2];    // [B,Q]
    float*       out    = (float*)d_out;          // [B,Q,BINS]

    const int BQ = in_sizes[2];                   // B*Q = 4096
    const int B  = BQ / QDIM;                     // 128

    unsigned int* pmask = (unsigned int*)d_ws;    // B*256 u32 = 128 KB

    build_mask_kernel<<<B, 256, 0, stream>>>(dtoks, pmask);
    drmm_hist_kernel<<<BQ, 256, 0, stream>>>(simmat, pmask, qtoks, out);
}

// Round 8
// 30.567 us; speedup vs baseline: 3.1746x; 1.0159x over previous
//
#include <hip/hip_runtime.h>
#include <math.h>

#define BINS 30
#define QDIM 32
#define DDIM 8192
#define NCOPY 32                 // one histogram copy per bank: addr = bin*32 + (t&31)

typedef float f32x4 __attribute__((ext_vector_type(4)));

// ---------- kernel 1: pre-packed per-thread validity nibbles ----------
// pmask[b*256 + t] bit (4*it + j) = (dtoks[b][it*1024 + 4*t + j] != 0)
__global__ __launch_bounds__(256) void build_mask_kernel(
    const int* __restrict__ dtoks,
    unsigned int* __restrict__ pmask)
{
    const int b = blockIdx.x;
    const int t = threadIdx.x;
    const int4* __restrict__ drow = reinterpret_cast<const int4*>(dtoks + (size_t)b * DDIM);
    unsigned int bits = 0u;
#pragma unroll
    for (int it = 0; it < 8; ++it) {
        const int4 dt = drow[it * 256 + t];
        bits |= (dt.x != 0 ? 1u : 0u) << (4 * it + 0);
        bits |= (dt.y != 0 ? 1u : 0u) << (4 * it + 1);
        bits |= (dt.z != 0 ? 1u : 0u) << (4 * it + 2);
        bits |= (dt.w != 0 ? 1u : 0u) << (4 * it + 3);
    }
    pmask[b * 256 + t] = bits;
}

// ---------- kernel 2: weighted histogram + log ----------
// Identical to R7 except simmat is read with NONTEMPORAL loads (stream-once
// data: bypass L1/L2 allocation on the read path).
__global__ __launch_bounds__(256, 8) void drmm_hist_kernel(
    const float* __restrict__ simmat,
    const unsigned int* __restrict__ pmask,
    const int*   __restrict__ qtoks,
    float*       __restrict__ out)
{
    const int bq = blockIdx.x;        // row index in [0, B*Q)
    const int b  = bq >> 5;           // Q == 32
    const int t  = threadIdx.x;
    const int c  = t & (NCOPY - 1);

    __shared__ int hist[32 * NCOPY];  // 4 KB; bins 0..29 used, padded to 32

    reinterpret_cast<int4*>(hist)[t] = int4{0, 0, 0, 0};

    if (qtoks[bq] == 0) {             // block-uniform early-out (padded query)
        if (t < BINS) out[(size_t)bq * BINS + t] = logf(1e-5f);
        return;
    }

    const unsigned int nib = pmask[b * 256 + t];   // this thread's 32 weight bits
    const f32x4* __restrict__ srow =
        reinterpret_cast<const f32x4*>(simmat + (size_t)bq * DDIM);

    __syncthreads();

    // 8192 elements / (256 threads * 4) = 8 iterations
#pragma unroll
    for (int it = 0; it < 8; ++it) {
        const f32x4 s = __builtin_nontemporal_load(&srow[it * 256 + t]);
        // bin = trunc((s + 1.000001f) * 14.5f)  == trunc(((s+1.000001f)/2)*29)
        const int bin0 = (int)((s.x + 1.000001f) * 14.5f);
        const int bin1 = (int)((s.y + 1.000001f) * 14.5f);
        const int bin2 = (int)((s.z + 1.000001f) * 14.5f);
        const int bin3 = (int)((s.w + 1.000001f) * 14.5f);

        atomicAdd(&hist[bin0 * NCOPY + c], (int)((nib >> (4 * it + 0)) & 1u));
        atomicAdd(&hist[bin1 * NCOPY + c], (int)((nib >> (4 * it + 1)) & 1u));
        atomicAdd(&hist[bin2 * NCOPY + c], (int)((nib >> (4 * it + 2)) & 1u));
        atomicAdd(&hist[bin3 * NCOPY + c], (int)((nib >> (4 * it + 3)) & 1u));
    }
    __syncthreads();

    // reduce 32 copies per bin: 240 threads -> (bin, j), then 8-lane shuffle tree
    if (t < BINS * 8) {
        const int bin = t >> 3;
        const int j   = t & 7;
        int p = hist[bin * NCOPY + j]      + hist[bin * NCOPY + j + 8]
              + hist[bin * NCOPY + j + 16] + hist[bin * NCOPY + j + 24];
        p += __shfl_xor(p, 1);
        p += __shfl_xor(p, 2);
        p += __shfl_xor(p, 4);
        if (j == 0) out[(size_t)bq * BINS + bin] = logf((float)p + 1e-5f);
    }
}

extern "C" void kernel_launch(void* const* d_in, const int* in_sizes, int n_in,
                              void* d_out, int out_size, void* d_ws, size_t ws_size,
                              hipStream_t stream) {
    const float* simmat = (const float*)d_in[0];  // [B,Q,D] f32
    const int*   dtoks  = (const int*)d_in[1];    // [B,D]
    const int*   qtoks  = (const int*)d_in[2];    // [B,Q]
    float*       out    = (float*)d_out;          // [B,Q,BINS]

    const int BQ = in_sizes[2];                   // B*Q = 4096
    const int B  = BQ / QDIM;                     // 128

    unsigned int* pmask = (unsigned int*)d_ws;    // B*256 u32 = 128 KB

    build_mask_kernel<<<B, 256, 0, stream>>>(dtoks, pmask);
    drmm_hist_kernel<<<BQ, 256, 0, stream>>>(simmat, pmask, qtoks, out);
}

// Round 9
// 29.320 us; speedup vs baseline: 3.3097x; 1.0425x over previous
//
#include <hip/hip_runtime.h>
#include <math.h>

#define BINS 30
#define QDIM 32
#define DDIM 8192
#define NCOPY 32                 // one histogram copy per bank: addr = bin*32 + (t&31)

typedef float f32x4 __attribute__((ext_vector_type(4)));

// ---------- kernel 1: pre-packed per-thread validity nibbles ----------
// pmask[b*256 + t] bit (4*it + j) = (dtoks[b][it*1024 + 4*t + j] != 0)
__global__ __launch_bounds__(256) void build_mask_kernel(
    const int* __restrict__ dtoks,
    unsigned int* __restrict__ pmask)
{
    const int b = blockIdx.x;
    const int t = threadIdx.x;
    const int4* __restrict__ drow = reinterpret_cast<const int4*>(dtoks + (size_t)b * DDIM);
    unsigned int bits = 0u;
#pragma unroll
    for (int it = 0; it < 8; ++it) {
        const int4 dt = drow[it * 256 + t];
        bits |= (dt.x != 0 ? 1u : 0u) << (4 * it + 0);
        bits |= (dt.y != 0 ? 1u : 0u) << (4 * it + 1);
        bits |= (dt.z != 0 ? 1u : 0u) << (4 * it + 2);
        bits |= (dt.w != 0 ? 1u : 0u) << (4 * it + 3);
    }
    pmask[b * 256 + t] = bits;
}

// ---------- kernel 2: weighted histogram + log ----------
// R8 + depth-8 MLP: all 8 float4 loads of the row issued back-to-back into
// registers (8 KB in flight per wave; 256 KB/CU) before any consumption.
__global__ __launch_bounds__(256, 8) void drmm_hist_kernel(
    const float* __restrict__ simmat,
    const unsigned int* __restrict__ pmask,
    const int*   __restrict__ qtoks,
    float*       __restrict__ out)
{
    const int bq = blockIdx.x;        // row index in [0, B*Q)
    const int b  = bq >> 5;           // Q == 32
    const int t  = threadIdx.x;
    const int c  = t & (NCOPY - 1);

    __shared__ int hist[32 * NCOPY];  // 4 KB; bins 0..29 used, padded to 32

    reinterpret_cast<int4*>(hist)[t] = int4{0, 0, 0, 0};

    if (qtoks[bq] == 0) {             // block-uniform early-out (padded query)
        if (t < BINS) out[(size_t)bq * BINS + t] = logf(1e-5f);
        return;
    }

    const unsigned int nib = pmask[b * 256 + t];   // this thread's 32 weight bits
    const f32x4* __restrict__ srow =
        reinterpret_cast<const f32x4*>(simmat + (size_t)bq * DDIM);

    // issue ALL 8 loads first (depth-8 MLP; constant indices -> stays in VGPRs)
    f32x4 s[8];
#pragma unroll
    for (int it = 0; it < 8; ++it)
        s[it] = __builtin_nontemporal_load(&srow[it * 256 + t]);

    __syncthreads();

    // consume (compiler emits counted vmcnt waits as each batch arrives)
#pragma unroll
    for (int it = 0; it < 8; ++it) {
        // bin = trunc((s + 1.000001f) * 14.5f)  == trunc(((s+1.000001f)/2)*29)
        const int bin0 = (int)((s[it].x + 1.000001f) * 14.5f);
        const int bin1 = (int)((s[it].y + 1.000001f) * 14.5f);
        const int bin2 = (int)((s[it].z + 1.000001f) * 14.5f);
        const int bin3 = (int)((s[it].w + 1.000001f) * 14.5f);

        atomicAdd(&hist[bin0 * NCOPY + c], (int)((nib >> (4 * it + 0)) & 1u));
        atomicAdd(&hist[bin1 * NCOPY + c], (int)((nib >> (4 * it + 1)) & 1u));
        atomicAdd(&hist[bin2 * NCOPY + c], (int)((nib >> (4 * it + 2)) & 1u));
        atomicAdd(&hist[bin3 * NCOPY + c], (int)((nib >> (4 * it + 3)) & 1u));
    }
    __syncthreads();

    // reduce 32 copies per bin: 240 threads -> (bin, j), then 8-lane shuffle tree
    if (t < BINS * 8) {
        const int bin = t >> 3;
        const int j   = t & 7;
        int p = hist[bin * NCOPY + j]      + hist[bin * NCOPY + j + 8]
              + hist[bin * NCOPY + j + 16] + hist[bin * NCOPY + j + 24];
        p += __shfl_xor(p, 1);
        p += __shfl_xor(p, 2);
        p += __shfl_xor(p, 4);
        if (j == 0) out[(size_t)bq * BINS + bin] = logf((float)p + 1e-5f);
    }
}

extern "C" void kernel_launch(void* const* d_in, const int* in_sizes, int n_in,
                              void* d_out, int out_size, void* d_ws, size_t ws_size,
                              hipStream_t stream) {
    const float* simmat = (const float*)d_in[0];  // [B,Q,D] f32
    const int*   dtoks  = (const int*)d_in[1];    // [B,D]
    const int*   qtoks  = (const int*)d_in[2];    // [B,Q]
    float*       out    = (float*)d_out;          // [B,Q,BINS]

    const int BQ = in_sizes[2];                   // B*Q = 4096
    const int B  = BQ / QDIM;                     // 128

    unsigned int* pmask = (unsigned int*)d_ws;    // B*256 u32 = 128 KB

    build_mask_kernel<<<B, 256, 0, stream>>>(dtoks, pmask);
    drmm_hist_kernel<<<BQ, 256, 0, stream>>>(simmat, pmask, qtoks, out);
}